// Round 1
// baseline (130.782 us; speedup 1.0000x reference)
//
#include <hip/hip_runtime.h>
#include <hip/hip_bf16.h>

#define B_ 32
#define D_ 512
#define N_ 1024
#define M_ 1024
#define BM 128
#define BK 64

typedef __attribute__((ext_vector_type(8))) short bf16x8;
typedef __attribute__((ext_vector_type(4))) float f32x4;
typedef __attribute__((ext_vector_type(4))) int   i32x4;

struct __align__(16) Smem {
    unsigned short As[BM * BK];   // swizzled [j=128][k=64] bf16, row = 128B = 8 granules of 16B
    unsigned short Bs[BM * BK];
    float red[4];
};

__device__ __forceinline__ unsigned map_f(float f) {
    unsigned b = __float_as_uint(f);
    return (b & 0x80000000u) ? ~b : (b | 0x80000000u);
}

// Stage a [BK=64 rows(d)] x [BM=128 cols(j)] fp32 global tile (row stride N_=M_=1024)
// into LDS as bf16 [j][k] with 16B-granule XOR swizzle: byte = j*128 + 16*(q ^ (j&7)) + 2*(k&7).
__device__ __forceinline__ void stage_tile(const float* __restrict__ src, char* lds, int t) {
    const int q  = t & 7;    // k-granule: k = 8q + dd
    const int jg = t >> 3;   // 0..31 -> j = 4*jg + i
    const float* p = src + (size_t)(q * 8) * N_ + jg * 4;
    float4 fl[8];
    #pragma unroll
    for (int dd = 0; dd < 8; ++dd)
        fl[dd] = *reinterpret_cast<const float4*>(p + (size_t)dd * N_);
    #pragma unroll
    for (int i = 0; i < 4; ++i) {
        const int j = jg * 4 + i;
        unsigned w[4];
        #pragma unroll
        for (int wi = 0; wi < 4; ++wi) {
            float2 f2 = make_float2(reinterpret_cast<const float*>(&fl[2 * wi])[i],
                                    reinterpret_cast<const float*>(&fl[2 * wi + 1])[i]);
            __hip_bfloat162 h2 = __float22bfloat162_rn(f2);
            w[wi] = *reinterpret_cast<unsigned*>(&h2);
        }
        i32x4 vv = { (int)w[0], (int)w[1], (int)w[2], (int)w[3] };
        *reinterpret_cast<i32x4*>(lds + j * 128 + 16 * (q ^ (j & 7))) = vv;
    }
}

__global__ __launch_bounds__(256, 2)
void gemm_max_kernel(const float* __restrict__ e1, const float* __restrict__ e2,
                     float* __restrict__ out) {
    __shared__ Smem sm;
    const int b  = blockIdx.z;
    const int tn = blockIdx.x * BM;   // n-tile base (from e1)
    const int tc = blockIdx.y * BM;   // m-tile base (from e2)
    const int t    = threadIdx.x;
    const int lane = t & 63;
    const int wave = t >> 6;
    const int l15  = lane & 15;
    const int l4   = lane >> 4;
    const int wr   = (wave >> 1) * 64;  // wave's A-row quadrant
    const int wc   = (wave & 1) * 64;   // wave's B-col quadrant

    const float* e1b = e1 + (size_t)b * D_ * N_ + tn;
    const float* e2b = e2 + (size_t)b * D_ * M_ + tc;

    f32x4 acc[4][4] = {};

    #pragma unroll 1
    for (int k0 = 0; k0 < D_; k0 += BK) {
        __syncthreads();   // previous compute done before overwriting LDS
        stage_tile(e1b + (size_t)k0 * N_, (char*)sm.As, t);
        stage_tile(e2b + (size_t)k0 * M_, (char*)sm.Bs, t);
        __syncthreads();
        #pragma unroll
        for (int kk = 0; kk < 2; ++kk) {
            bf16x8 afrag[4], bfrag[4];
            const int q = 4 * kk + l4;
            #pragma unroll
            for (int m = 0; m < 4; ++m) {
                const int j = wr + m * 16 + l15;
                afrag[m] = *reinterpret_cast<const bf16x8*>(
                    (char*)sm.As + j * 128 + 16 * (q ^ (j & 7)));
            }
            #pragma unroll
            for (int n = 0; n < 4; ++n) {
                const int j = wc + n * 16 + l15;
                bfrag[n] = *reinterpret_cast<const bf16x8*>(
                    (char*)sm.Bs + j * 128 + 16 * (q ^ (j & 7)));
            }
            #pragma unroll
            for (int m = 0; m < 4; ++m)
                #pragma unroll
                for (int n = 0; n < 4; ++n)
                    acc[m][n] = __builtin_amdgcn_mfma_f32_16x16x32_bf16(
                        afrag[m], bfrag[n], acc[m][n], 0, 0, 0);
        }
    }

    // max over this thread's 64 accumulator values
    float tmax = acc[0][0][0];
    #pragma unroll
    for (int m = 0; m < 4; ++m)
        #pragma unroll
        for (int n = 0; n < 4; ++n)
            #pragma unroll
            for (int i = 0; i < 4; ++i)
                tmax = fmaxf(tmax, acc[m][n][i]);

    #pragma unroll
    for (int off = 32; off; off >>= 1)
        tmax = fmaxf(tmax, __shfl_xor(tmax, off));
    if (lane == 0) sm.red[wave] = tmax;
    __syncthreads();
    if (t == 0) {
        float m4 = fmaxf(fmaxf(sm.red[0], sm.red[1]), fmaxf(sm.red[2], sm.red[3]));
        atomicMax(reinterpret_cast<unsigned*>(out) + b, map_f(m4));
    }
}

__global__ void finalize_kernel(float* out) {
    const int i = threadIdx.x;
    unsigned u = reinterpret_cast<unsigned*>(out)[i];
    out[i] = __uint_as_float((u & 0x80000000u) ? (u ^ 0x80000000u) : ~u);
}

extern "C" void kernel_launch(void* const* d_in, const int* in_sizes, int n_in,
                              void* d_out, int out_size, void* d_ws, size_t ws_size,
                              hipStream_t stream) {
    const float* e1 = (const float*)d_in[0];
    const float* e2 = (const float*)d_in[1];
    float* out = (float*)d_out;

    hipMemsetAsync(d_out, 0, B_ * sizeof(float), stream);  // 0 == -inf under map_f ordering

    dim3 grid(N_ / BM, M_ / BM, B_);
    gemm_max_kernel<<<grid, 256, 0, stream>>>(e1, e2, out);
    finalize_kernel<<<1, B_, 0, stream>>>(out);
}

// Round 2
// 125.633 us; speedup vs baseline: 1.0410x; 1.0410x over previous
//
#include <hip/hip_runtime.h>
#include <hip/hip_bf16.h>

#define B_ 32
#define D_ 512
#define N_ 1024
#define M_ 1024
#define BM 128
#define BK 64
#define NSTEP (D_ / BK)   // 8

typedef __attribute__((ext_vector_type(8))) short bf16x8;
typedef __attribute__((ext_vector_type(4))) float f32x4;
typedef __attribute__((ext_vector_type(4))) int   i32x4;

struct __align__(16) Smem {
    unsigned short As[2][BM * BK];   // swizzled [j=128][k=64] bf16, row = 128B = 8 granules
    unsigned short Bs[2][BM * BK];
    float red[4];
};

__device__ __forceinline__ unsigned map_f(float f) {
    unsigned b = __float_as_uint(f);
    return (b & 0x80000000u) ? ~b : (b | 0x80000000u);
}

// Issue 8 float4 loads of a [BK=64]x[BM=128] fp32 tile slice for this thread.
__device__ __forceinline__ void load8(const float* __restrict__ src, int t, float4* fl) {
    const int q  = t & 7;    // k-granule
    const int jg = t >> 3;   // col group
    const float* p = src + (size_t)(q * 8) * N_ + jg * 4;
    #pragma unroll
    for (int dd = 0; dd < 8; ++dd)
        fl[dd] = *reinterpret_cast<const float4*>(p + (size_t)dd * N_);
}

// Convert + write this thread's slice into LDS with 16B-granule XOR swizzle:
// byte = j*128 + 16*(q ^ (j&7)) + 2*(k&7)
__device__ __forceinline__ void flush8(const float4* fl, char* lds, int t) {
    const int q  = t & 7;
    const int jg = t >> 3;
    #pragma unroll
    for (int i = 0; i < 4; ++i) {
        const int j = jg * 4 + i;
        unsigned w[4];
        #pragma unroll
        for (int wi = 0; wi < 4; ++wi) {
            float2 f2 = make_float2(reinterpret_cast<const float*>(&fl[2 * wi])[i],
                                    reinterpret_cast<const float*>(&fl[2 * wi + 1])[i]);
            __hip_bfloat162 h2 = __float22bfloat162_rn(f2);
            w[wi] = *reinterpret_cast<unsigned*>(&h2);
        }
        i32x4 vv = { (int)w[0], (int)w[1], (int)w[2], (int)w[3] };
        *reinterpret_cast<i32x4*>(lds + j * 128 + 16 * (q ^ (j & 7))) = vv;
    }
}

__global__ __launch_bounds__(256, 2)
void gemm_max_kernel(const float* __restrict__ e1, const float* __restrict__ e2,
                     float* __restrict__ out) {
    __shared__ Smem sm;

    // XCD-aware bijective swizzle: 2048 blocks, 8 XCDs -> each XCD gets 256
    // consecutive logical blocks = 4 whole batches (~4MB working set ~ one L2).
    const int wg  = blockIdx.x;
    const int swz = (wg & 7) * (2048 / 8) + (wg >> 3);
    const int b    = swz >> 6;          // 64 tiles per batch
    const int tile = swz & 63;
    const int tn = (tile >> 3) * BM;    // n-tile (e1 cols)
    const int tc = (tile & 7) * BM;     // m-tile (e2 cols)

    const int t    = threadIdx.x;
    const int lane = t & 63;
    const int wave = t >> 6;
    const int l15  = lane & 15;
    const int l4   = lane >> 4;
    const int wr   = (wave >> 1) * 64;
    const int wc   = (wave & 1) * 64;

    const float* e1b = e1 + (size_t)b * D_ * N_ + tn;
    const float* e2b = e2 + (size_t)b * D_ * M_ + tc;

    f32x4 acc[4][4] = {};
    float4 flA[8], flB[8];

    // Prologue: stage tile 0, issue loads for tile 1.
    load8(e1b, t, flA);
    load8(e2b, t, flB);
    flush8(flA, (char*)sm.As[0], t);
    flush8(flB, (char*)sm.Bs[0], t);
    load8(e1b + (size_t)BK * N_, t, flA);
    load8(e2b + (size_t)BK * M_, t, flB);

    int cur = 0;
    #pragma unroll 1
    for (int ks = 0; ks < NSTEP; ++ks) {
        __syncthreads();   // buf[cur] writes visible to all waves
        const char* Ab = (const char*)sm.As[cur];
        const char* Bb = (const char*)sm.Bs[cur];
        #pragma unroll
        for (int kk = 0; kk < 2; ++kk) {
            bf16x8 afrag[4], bfrag[4];
            const int q = 4 * kk + l4;
            #pragma unroll
            for (int m = 0; m < 4; ++m) {
                const int j = wr + m * 16 + l15;
                afrag[m] = *reinterpret_cast<const bf16x8*>(Ab + j * 128 + 16 * (q ^ (j & 7)));
            }
            #pragma unroll
            for (int n = 0; n < 4; ++n) {
                const int j = wc + n * 16 + l15;
                bfrag[n] = *reinterpret_cast<const bf16x8*>(Bb + j * 128 + 16 * (q ^ (j & 7)));
            }
            #pragma unroll
            for (int m = 0; m < 4; ++m)
                #pragma unroll
                for (int n = 0; n < 4; ++n)
                    acc[m][n] = __builtin_amdgcn_mfma_f32_16x16x32_bf16(
                        afrag[m], bfrag[n], acc[m][n], 0, 0, 0);
        }
        // Pipeline tail of this iteration: land tile ks+1 (loads issued one
        // full compute-phase ago), then issue loads for tile ks+2.
        if (ks < NSTEP - 1) {
            flush8(flA, (char*)sm.As[cur ^ 1], t);
            flush8(flB, (char*)sm.Bs[cur ^ 1], t);
            if (ks < NSTEP - 2) {
                load8(e1b + (size_t)(ks + 2) * BK * N_, t, flA);
                load8(e2b + (size_t)(ks + 2) * BK * M_, t, flB);
            }
        }
        cur ^= 1;
    }

    // Max over this thread's 64 accumulator values.
    float tmax = acc[0][0][0];
    #pragma unroll
    for (int m = 0; m < 4; ++m)
        #pragma unroll
        for (int n = 0; n < 4; ++n)
            #pragma unroll
            for (int i = 0; i < 4; ++i)
                tmax = fmaxf(tmax, acc[m][n][i]);

    #pragma unroll
    for (int off = 32; off; off >>= 1)
        tmax = fmaxf(tmax, __shfl_xor(tmax, off));
    if (lane == 0) sm.red[wave] = tmax;
    __syncthreads();
    if (t == 0) {
        float m4 = fmaxf(fmaxf(sm.red[0], sm.red[1]), fmaxf(sm.red[2], sm.red[3]));
        atomicMax(reinterpret_cast<unsigned*>(out) + b, map_f(m4));
    }
}

__global__ void finalize_kernel(float* out) {
    const int i = threadIdx.x;
    unsigned u = reinterpret_cast<unsigned*>(out)[i];
    out[i] = __uint_as_float((u & 0x80000000u) ? (u ^ 0x80000000u) : ~u);
}

extern "C" void kernel_launch(void* const* d_in, const int* in_sizes, int n_in,
                              void* d_out, int out_size, void* d_ws, size_t ws_size,
                              hipStream_t stream) {
    const float* e1 = (const float*)d_in[0];
    const float* e2 = (const float*)d_in[1];
    float* out = (float*)d_out;

    hipMemsetAsync(d_out, 0, B_ * sizeof(float), stream);  // 0 == -inf under map_f

    gemm_max_kernel<<<dim3(2048), 256, 0, stream>>>(e1, e2, out);
    finalize_kernel<<<1, B_, 0, stream>>>(out);
}

// Round 3
// 79.205 us; speedup vs baseline: 1.6512x; 1.5862x over previous
//
#include <hip/hip_runtime.h>
#include <hip/hip_bf16.h>

#define B_ 32
#define D_ 512
#define N_ 1024
#define M_ 1024
#define BM 128
#define BK 64
#define NSTEP (D_ / BK)   // 8

typedef __attribute__((ext_vector_type(8))) short bf16x8;
typedef __attribute__((ext_vector_type(4))) float f32x4;
typedef __attribute__((ext_vector_type(4))) int   i32x4;
typedef unsigned short ushort_t;

__device__ __forceinline__ unsigned map_f(float f) {
    unsigned b = __float_as_uint(f);
    return (b & 0x80000000u) ? ~b : (b | 0x80000000u);
}

// ============================================================================
// Pass 1: convert fp32 [b][d=512][j=1024] -> bf16 [b][j=1024][d=512]
// 64x64 tiles through LDS; 8192 blocks x 256 threads.
// ============================================================================
__global__ __launch_bounds__(256)
void cvt_transpose_kernel(const float* __restrict__ e1, const float* __restrict__ e2,
                          ushort_t* __restrict__ w1, ushort_t* __restrict__ w2) {
    __shared__ __align__(16) ushort_t tile[64][72];   // pad: 144B row stride (16-aligned)
    const int id  = blockIdx.x;
    const int arr = id >> 12;           // 4096 tiles per array
    const int rem = id & 4095;
    const int b   = rem >> 7;           // 128 tiles per batch (16 jt x 8 kt)
    const int jt  = (rem & 127) >> 3;
    const int kt  = rem & 7;
    const float* src = (arr ? e2 : e1) + (size_t)b * D_ * N_ + (size_t)(kt * 64) * N_ + jt * 64;
    ushort_t*    dst = (arr ? w2 : w1) + (size_t)b * N_ * D_ + (size_t)(jt * 64) * D_ + kt * 64;
    const int t = threadIdx.x;
    #pragma unroll
    for (int r = 0; r < 4; ++r) {
        const int kl   = (t >> 4) + 16 * r;   // 0..63
        const int joff = (t & 15) * 4;        // 0..60
        float4 f = *reinterpret_cast<const float4*>(src + (size_t)kl * N_ + joff);
        __hip_bfloat162 h0 = __float22bfloat162_rn(make_float2(f.x, f.y));
        __hip_bfloat162 h1 = __float22bfloat162_rn(make_float2(f.z, f.w));
        const ushort_t* p0 = reinterpret_cast<const ushort_t*>(&h0);
        const ushort_t* p1 = reinterpret_cast<const ushort_t*>(&h1);
        tile[joff + 0][kl] = p0[0];
        tile[joff + 1][kl] = p0[1];
        tile[joff + 2][kl] = p1[0];
        tile[joff + 3][kl] = p1[1];
    }
    __syncthreads();
    #pragma unroll
    for (int r = 0; r < 2; ++r) {
        const int jl   = (t >> 3) + 32 * r;   // 0..63
        const int koff = (t & 7) * 8;         // 0..56
        i32x4 v = *reinterpret_cast<const i32x4*>(&tile[jl][koff]);
        *reinterpret_cast<i32x4*>(dst + (size_t)jl * D_ + koff) = v;
    }
}

// ============================================================================
// Pass 2: bf16 GEMM-max, m97-style 2-phase with global_load_lds staging.
// LDS layout per tile: byte = j*128 + 16*(q ^ (j&7)), q = k-granule (8 bf16).
// Staging writes LINEAR LDS; the swizzle is applied to the GLOBAL source addr.
// ============================================================================
struct __align__(16) GSmem {
    ushort_t As[2][BM * BK];
    ushort_t Bs[2][BM * BK];
    float red[4];
};

__device__ __forceinline__ void stage_lds(const ushort_t* __restrict__ wsrc,
                                          ushort_t* lds_tile, int k0, int wave, int lane) {
    #pragma unroll
    for (int i = 0; i < 4; ++i) {
        const int jb = wave * 32 + i * 8;
        const int j  = jb + (lane >> 3);
        const int q  = (lane & 7) ^ (j & 7);           // inverse-swizzled source granule
        const char* gp = (const char*)wsrc + (size_t)j * (D_ * 2) + k0 * 2 + q * 16;
        char* lp = (char*)lds_tile + (wave * 4 + i) * 1024;   // wave-uniform base
        __builtin_amdgcn_global_load_lds(
            (const __attribute__((address_space(1))) unsigned int*)gp,
            (__attribute__((address_space(3))) unsigned int*)lp, 16, 0, 0);
    }
}

__global__ __launch_bounds__(256, 2)
void gemm_bf16_kernel(const ushort_t* __restrict__ w1, const ushort_t* __restrict__ w2,
                      float* __restrict__ out) {
    __shared__ GSmem sm;
    const int wg  = blockIdx.x;
    const int swz = (wg & 7) * 256 + (wg >> 3);   // XCD swizzle (2048 % 8 == 0)
    const int b    = swz >> 6;
    const int tile = swz & 63;
    const int tn = (tile >> 3) * BM;
    const int tc = (tile & 7) * BM;

    const int t    = threadIdx.x;
    const int lane = t & 63;
    const int wave = t >> 6;
    const int l15  = lane & 15;
    const int l4   = lane >> 4;
    const int wr   = (wave >> 1) * 64;
    const int wc   = (wave & 1) * 64;

    const ushort_t* Aw = w1 + (size_t)b * N_ * D_ + (size_t)tn * D_;
    const ushort_t* Bw = w2 + (size_t)b * M_ * D_ + (size_t)tc * D_;

    f32x4 acc[4][4] = {};

    stage_lds(Aw, sm.As[0], 0, wave, lane);
    stage_lds(Bw, sm.Bs[0], 0, wave, lane);
    asm volatile("s_waitcnt vmcnt(0)" ::: "memory");
    __syncthreads();

    int cur = 0;
    #pragma unroll 1
    for (int ks = 0; ks < NSTEP; ++ks) {
        if (ks < NSTEP - 1) {   // async prefetch of next K-tile while computing this one
            stage_lds(Aw, sm.As[cur ^ 1], (ks + 1) * BK, wave, lane);
            stage_lds(Bw, sm.Bs[cur ^ 1], (ks + 1) * BK, wave, lane);
        }
        const char* Ab = (const char*)sm.As[cur];
        const char* Bb = (const char*)sm.Bs[cur];
        #pragma unroll
        for (int kk = 0; kk < 2; ++kk) {
            bf16x8 afrag[4], bfrag[4];
            const int q = 4 * kk + l4;
            #pragma unroll
            for (int m = 0; m < 4; ++m) {
                const int j = wr + m * 16 + l15;
                afrag[m] = *reinterpret_cast<const bf16x8*>(Ab + j * 128 + 16 * (q ^ (j & 7)));
            }
            #pragma unroll
            for (int n = 0; n < 4; ++n) {
                const int j = wc + n * 16 + l15;
                bfrag[n] = *reinterpret_cast<const bf16x8*>(Bb + j * 128 + 16 * (q ^ (j & 7)));
            }
            #pragma unroll
            for (int m = 0; m < 4; ++m)
                #pragma unroll
                for (int n = 0; n < 4; ++n)
                    acc[m][n] = __builtin_amdgcn_mfma_f32_16x16x32_bf16(
                        afrag[m], bfrag[n], acc[m][n], 0, 0, 0);
        }
        asm volatile("s_waitcnt vmcnt(0)" ::: "memory");   // prefetched tile landed
        __syncthreads();
        cur ^= 1;
    }

    float tmax = acc[0][0][0];
    #pragma unroll
    for (int m = 0; m < 4; ++m)
        #pragma unroll
        for (int n = 0; n < 4; ++n)
            #pragma unroll
            for (int i = 0; i < 4; ++i)
                tmax = fmaxf(tmax, acc[m][n][i]);
    #pragma unroll
    for (int off = 32; off; off >>= 1)
        tmax = fmaxf(tmax, __shfl_xor(tmax, off));
    if (lane == 0) sm.red[wave] = tmax;
    __syncthreads();
    if (t == 0) {
        float m4 = fmaxf(fmaxf(sm.red[0], sm.red[1]), fmaxf(sm.red[2], sm.red[3]));
        atomicMax(reinterpret_cast<unsigned*>(out) + b, map_f(m4));
    }
}

// ============================================================================
// Fallback (ws too small): round-2 fused fp32->bf16 staging kernel.
// ============================================================================
struct __align__(16) FSmem {
    ushort_t As[2][BM * BK];
    ushort_t Bs[2][BM * BK];
    float red[4];
};

__device__ __forceinline__ void load8(const float* __restrict__ src, int t, float4* fl) {
    const int q  = t & 7;
    const int jg = t >> 3;
    const float* p = src + (size_t)(q * 8) * N_ + jg * 4;
    #pragma unroll
    for (int dd = 0; dd < 8; ++dd)
        fl[dd] = *reinterpret_cast<const float4*>(p + (size_t)dd * N_);
}

__device__ __forceinline__ void flush8(const float4* fl, char* lds, int t) {
    const int q  = t & 7;
    const int jg = t >> 3;
    #pragma unroll
    for (int i = 0; i < 4; ++i) {
        const int j = jg * 4 + i;
        unsigned w[4];
        #pragma unroll
        for (int wi = 0; wi < 4; ++wi) {
            float2 f2 = make_float2(reinterpret_cast<const float*>(&fl[2 * wi])[i],
                                    reinterpret_cast<const float*>(&fl[2 * wi + 1])[i]);
            __hip_bfloat162 h2 = __float22bfloat162_rn(f2);
            w[wi] = *reinterpret_cast<unsigned*>(&h2);
        }
        i32x4 vv = { (int)w[0], (int)w[1], (int)w[2], (int)w[3] };
        *reinterpret_cast<i32x4*>(lds + j * 128 + 16 * (q ^ (j & 7))) = vv;
    }
}

__global__ __launch_bounds__(256, 2)
void gemm_max_kernel(const float* __restrict__ e1, const float* __restrict__ e2,
                     float* __restrict__ out) {
    __shared__ FSmem sm;
    const int wg  = blockIdx.x;
    const int swz = (wg & 7) * 256 + (wg >> 3);
    const int b    = swz >> 6;
    const int tile = swz & 63;
    const int tn = (tile >> 3) * BM;
    const int tc = (tile & 7) * BM;
    const int t    = threadIdx.x;
    const int lane = t & 63;
    const int wave = t >> 6;
    const int l15  = lane & 15;
    const int l4   = lane >> 4;
    const int wr   = (wave >> 1) * 64;
    const int wc   = (wave & 1) * 64;
    const float* e1b = e1 + (size_t)b * D_ * N_ + tn;
    const float* e2b = e2 + (size_t)b * D_ * M_ + tc;
    f32x4 acc[4][4] = {};
    float4 flA[8], flB[8];
    load8(e1b, t, flA);
    load8(e2b, t, flB);
    flush8(flA, (char*)sm.As[0], t);
    flush8(flB, (char*)sm.Bs[0], t);
    load8(e1b + (size_t)BK * N_, t, flA);
    load8(e2b + (size_t)BK * M_, t, flB);
    int cur = 0;
    #pragma unroll 1
    for (int ks = 0; ks < NSTEP; ++ks) {
        __syncthreads();
        const char* Ab = (const char*)sm.As[cur];
        const char* Bb = (const char*)sm.Bs[cur];
        #pragma unroll
        for (int kk = 0; kk < 2; ++kk) {
            bf16x8 afrag[4], bfrag[4];
            const int q = 4 * kk + l4;
            #pragma unroll
            for (int m = 0; m < 4; ++m) {
                const int j = wr + m * 16 + l15;
                afrag[m] = *reinterpret_cast<const bf16x8*>(Ab + j * 128 + 16 * (q ^ (j & 7)));
            }
            #pragma unroll
            for (int n = 0; n < 4; ++n) {
                const int j = wc + n * 16 + l15;
                bfrag[n] = *reinterpret_cast<const bf16x8*>(Bb + j * 128 + 16 * (q ^ (j & 7)));
            }
            #pragma unroll
            for (int m = 0; m < 4; ++m)
                #pragma unroll
                for (int n = 0; n < 4; ++n)
                    acc[m][n] = __builtin_amdgcn_mfma_f32_16x16x32_bf16(
                        afrag[m], bfrag[n], acc[m][n], 0, 0, 0);
        }
        if (ks < NSTEP - 1) {
            flush8(flA, (char*)sm.As[cur ^ 1], t);
            flush8(flB, (char*)sm.Bs[cur ^ 1], t);
            if (ks < NSTEP - 2) {
                load8(e1b + (size_t)(ks + 2) * BK * N_, t, flA);
                load8(e2b + (size_t)(ks + 2) * BK * M_, t, flB);
            }
        }
        cur ^= 1;
    }
    float tmax = acc[0][0][0];
    #pragma unroll
    for (int m = 0; m < 4; ++m)
        #pragma unroll
        for (int n = 0; n < 4; ++n)
            #pragma unroll
            for (int i = 0; i < 4; ++i)
                tmax = fmaxf(tmax, acc[m][n][i]);
    #pragma unroll
    for (int off = 32; off; off >>= 1)
        tmax = fmaxf(tmax, __shfl_xor(tmax, off));
    if (lane == 0) sm.red[wave] = tmax;
    __syncthreads();
    if (t == 0) {
        float m4 = fmaxf(fmaxf(sm.red[0], sm.red[1]), fmaxf(sm.red[2], sm.red[3]));
        atomicMax(reinterpret_cast<unsigned*>(out) + b, map_f(m4));
    }
}

__global__ void finalize_kernel(float* out) {
    const int i = threadIdx.x;
    unsigned u = reinterpret_cast<unsigned*>(out)[i];
    out[i] = __uint_as_float((u & 0x80000000u) ? (u ^ 0x80000000u) : ~u);
}

extern "C" void kernel_launch(void* const* d_in, const int* in_sizes, int n_in,
                              void* d_out, int out_size, void* d_ws, size_t ws_size,
                              hipStream_t stream) {
    const float* e1 = (const float*)d_in[0];
    const float* e2 = (const float*)d_in[1];
    float* out = (float*)d_out;

    hipMemsetAsync(d_out, 0, B_ * sizeof(float), stream);  // 0 == -inf under map_f

    const size_t need = (size_t)2 * B_ * N_ * D_ * sizeof(ushort_t);  // 64 MB
    if (ws_size >= need) {
        ushort_t* w1 = (ushort_t*)d_ws;
        ushort_t* w2 = w1 + (size_t)B_ * N_ * D_;
        cvt_transpose_kernel<<<8192, 256, 0, stream>>>(e1, e2, w1, w2);
        gemm_bf16_kernel<<<2048, 256, 0, stream>>>(w1, w2, out);
    } else {
        gemm_max_kernel<<<2048, 256, 0, stream>>>(e1, e2, out);
    }
    finalize_kernel<<<1, B_, 0, stream>>>(out);
}